// Round 6
// baseline (29.047 us; speedup 1.0000x reference)
//
#include <hip/hip_runtime.h>
#include <math.h>

#define NQ 4
#define NL 6
#define BATCH 524288

struct C2 { float re, im; };
typedef float f32x16 __attribute__((ext_vector_type(16)));

__device__ __forceinline__ C2 cmul(C2 a, C2 b) {
    return C2{ __builtin_fmaf(a.re, b.re, -a.im * b.im),
               __builtin_fmaf(a.re, b.im,  a.im * b.re) };
}

// ---------------------------------------------------------------------------
// Prep kernel (parallel, 1 block x 64 threads) — unchanged (verified R2-R5).
// Phase 1: lanes 0..23 build fused U = RZ*RY*RX gates -> LDS.
// Phase 2: lanes 0..31 (lane = 2*j + h) evolve basis column j; 8 complex
// amps in registers; cross-half ops via __shfl_xor. Folds (-i)^popcount(j)
// and stores V[r][j] interleaved (re,im) at V[(r*16+j)*2 + {0,1}].
// ---------------------------------------------------------------------------
__global__ __launch_bounds__(64) void prep_kernel(const float* __restrict__ w,
                                                  float* __restrict__ V) {
    __shared__ float sU[NL * NQ * 8];
    const int lane = threadIdx.x;

    if (lane < NL * NQ) {
        const float a = w[lane * 3 + 0];
        const float b = w[lane * 3 + 1];
        const float g = w[lane * 3 + 2];
        float ca, sa, cb, sb, cg, sg;
        sincosf(0.5f * a, &sa, &ca);
        sincosf(0.5f * b, &sb, &cb);
        sincosf(0.5f * g, &sg, &cg);
        C2 M00{cb * ca,  sb * sa};
        C2 M01{-sb * ca, -cb * sa};
        C2 M10{sb * ca,  -cb * sa};
        C2 M11{cb * ca,  -sb * sa};
        C2 em{cg, -sg}, ep{cg, sg};
        C2 U00 = cmul(em, M00), U01 = cmul(em, M01);
        C2 U10 = cmul(ep, M10), U11 = cmul(ep, M11);
        float* o = &sU[lane * 8];
        o[0] = U00.re; o[1] = U00.im; o[2] = U01.re; o[3] = U01.im;
        o[4] = U10.re; o[5] = U10.im; o[6] = U11.re; o[7] = U11.im;
    }
    __syncthreads();

    if (lane >= 32) return;
    const int j = lane >> 1;
    const int h = lane & 1;

    C2 st[8];
#pragma unroll
    for (int i = 0; i < 8; ++i) st[i] = C2{0.f, 0.f};
    if ((j >> 3) == h) st[j & 7].re = 1.f;

#define APPLY_PAIR(i0, i1)                                                     \
    {                                                                          \
        C2 a0 = st[i0], a1 = st[i1];                                           \
        st[i0].re = U00.re*a0.re - U00.im*a0.im + U01.re*a1.re - U01.im*a1.im; \
        st[i0].im = U00.re*a0.im + U00.im*a0.re + U01.re*a1.im + U01.im*a1.re; \
        st[i1].re = U10.re*a0.re - U10.im*a0.im + U11.re*a1.re - U11.im*a1.im; \
        st[i1].im = U10.re*a0.im + U10.im*a0.re + U11.re*a1.im + U11.im*a1.re; \
    }
#define SWAPST(a, b) { C2 t_ = st[a]; st[a] = st[b]; st[b] = t_; }

#pragma unroll
    for (int l = 0; l < NL; ++l) {
        {   // CNOT(q0 mask8, q1 mask4): if h==1, permute i <-> i^4
            C2 ns[8];
#pragma unroll
            for (int i = 0; i < 8; ++i) {
                ns[i].re = h ? st[i ^ 4].re : st[i].re;
                ns[i].im = h ? st[i ^ 4].im : st[i].im;
            }
#pragma unroll
            for (int i = 0; i < 8; ++i) st[i] = ns[i];
        }
        SWAPST(4, 6) SWAPST(5, 7)           // CNOT(q1, q2)
        SWAPST(2, 3) SWAPST(6, 7)           // CNOT(q2, q3)
#pragma unroll
        for (int i = 1; i < 8; i += 2) {    // CNOT(q3, q0)
            st[i].re = __shfl_xor(st[i].re, 1);
            st[i].im = __shfl_xor(st[i].im, 1);
        }
        {   // qubit 0 gate (cross-lane)
            const float* u = &sU[(l * NQ + 0) * 8];
            C2 U00{u[0], u[1]}, U01{u[2], u[3]}, U10{u[4], u[5]}, U11{u[6], u[7]};
            C2 Ud = h ? U11 : U00;
            C2 Uo = h ? U10 : U01;
#pragma unroll
            for (int i = 0; i < 8; ++i) {
                C2 p{__shfl_xor(st[i].re, 1), __shfl_xor(st[i].im, 1)};
                C2 a = st[i];
                st[i].re = Ud.re*a.re - Ud.im*a.im + Uo.re*p.re - Uo.im*p.im;
                st[i].im = Ud.re*a.im + Ud.im*a.re + Uo.re*p.im + Uo.im*p.re;
            }
        }
        {   // qubit 1 gate
            const float* u = &sU[(l * NQ + 1) * 8];
            C2 U00{u[0], u[1]}, U01{u[2], u[3]}, U10{u[4], u[5]}, U11{u[6], u[7]};
            APPLY_PAIR(0, 4) APPLY_PAIR(1, 5) APPLY_PAIR(2, 6) APPLY_PAIR(3, 7)
        }
        {   // qubit 2 gate
            const float* u = &sU[(l * NQ + 2) * 8];
            C2 U00{u[0], u[1]}, U01{u[2], u[3]}, U10{u[4], u[5]}, U11{u[6], u[7]};
            APPLY_PAIR(0, 2) APPLY_PAIR(1, 3) APPLY_PAIR(4, 6) APPLY_PAIR(5, 7)
        }
        {   // qubit 3 gate
            const float* u = &sU[(l * NQ + 3) * 8];
            C2 U00{u[0], u[1]}, U01{u[2], u[3]}, U10{u[4], u[5]}, U11{u[6], u[7]};
            APPLY_PAIR(0, 1) APPLY_PAIR(2, 3) APPLY_PAIR(4, 5) APPLY_PAIR(6, 7)
        }
    }

    const int p4 = __popc(j) & 3;
    const float fr = (p4 == 0) ? 1.f : (p4 == 2) ? -1.f : 0.f;
    const float fi = (p4 == 1) ? -1.f : (p4 == 3) ? 1.f : 0.f;
#pragma unroll
    for (int i = 0; i < 8; ++i) {
        const int r = h * 8 + i;
        float re = st[i].re * fr - st[i].im * fi;
        float im = st[i].re * fi + st[i].im * fr;
        V[(r * 16 + j) * 2 + 0] = re;
        V[(r * 16 + j) * 2 + 1] = im;
    }
#undef APPLY_PAIR
#undef SWAPST
}

// ---------------------------------------------------------------------------
// Main kernel v2: SGPR-resident V, rows split across waves.
// Block = 512 threads (8 waves) processes 64 batch elements.
// Wave w owns rows {2w, 2w+1}: 64 floats, loaded ONCE into 64 SGPRs via
// 4x s_load_dwordx16 + a single lgkmcnt(0). Every V access afterwards is a
// free SGPR operand in v_fma (1 SGPR/VALU-instr - legal). ev_q is separable
// over rows, so each wave computes a signed partial and the block reduces
// through LDS. Broadcast traffic: 2 KB/thread -> 256 B/wave.
// ---------------------------------------------------------------------------
__global__ __launch_bounds__(512) void qmain_kernel(const float4* __restrict__ x,
                                                    const float* __restrict__ V,
                                                    float4* __restrict__ out) {
    __shared__ float4 sEv[8 * 64];
    const int tid = threadIdx.x;
    const int e   = tid & 63;
    const int w   = __builtin_amdgcn_readfirstlane(tid >> 6);  // wave id 0..7

    // ---- this wave's 2 rows into SGPRs (one wait, once per thread) ----
    const float* rowp = V + w * 64;   // rows 2w,2w+1: 64 floats
    f32x16 ra, rb, rc, rd;            // ra,rb = row 2w (cols 0-7 | 8-15); rc,rd = row 2w+1
    asm volatile("s_load_dwordx16 %0, %4, 0x0\n\t"
                 "s_load_dwordx16 %1, %4, 0x40\n\t"
                 "s_load_dwordx16 %2, %4, 0x80\n\t"
                 "s_load_dwordx16 %3, %4, 0xC0\n\t"
                 "s_waitcnt lgkmcnt(0)"
                 : "=s"(ra), "=s"(rb), "=s"(rc), "=s"(rd)
                 : "s"(rowp));

    // ---- per-element Kronecker vector m (duplicated per wave: ~26 VALU) ----
    const float4 xv = x[blockIdx.x * 64 + e];
    float c0, s0, c1, s1, c2, s2, c3, s3;
    __sincosf(0.5f * xv.x, &s0, &c0);
    __sincosf(0.5f * xv.y, &s1, &c1);
    __sincosf(0.5f * xv.z, &s2, &c2);
    __sincosf(0.5f * xv.w, &s3, &c3);
    float m[16];
    {
        float ab[4];
        ab[0] = c0 * c1; ab[1] = c0 * s1; ab[2] = s0 * c1; ab[3] = s0 * s1;
        float abc[8];
#pragma unroll
        for (int k = 0; k < 4; ++k) { abc[2 * k] = ab[k] * c2; abc[2 * k + 1] = ab[k] * s2; }
#pragma unroll
        for (int k = 0; k < 8; ++k) { m[2 * k] = abc[k] * c3; m[2 * k + 1] = abc[k] * s3; }
    }

    // ---- two rows' psi, all V operands from SGPRs ----
    float re0 = 0.f, im0 = 0.f, re1 = 0.f, im1 = 0.f;
#pragma unroll
    for (int c = 0; c < 8; ++c) {
        re0 = __builtin_fmaf(m[c], ra[2 * c],     re0);
        im0 = __builtin_fmaf(m[c], ra[2 * c + 1], im0);
        re1 = __builtin_fmaf(m[c], rc[2 * c],     re1);
        im1 = __builtin_fmaf(m[c], rc[2 * c + 1], im1);
    }
#pragma unroll
    for (int c = 0; c < 8; ++c) {
        re0 = __builtin_fmaf(m[8 + c], rb[2 * c],     re0);
        im0 = __builtin_fmaf(m[8 + c], rb[2 * c + 1], im0);
        re1 = __builtin_fmaf(m[8 + c], rd[2 * c],     re1);
        im1 = __builtin_fmaf(m[8 + c], rd[2 * c + 1], im1);
    }
    const float p0 = __builtin_fmaf(re0, re0, im0 * im0);
    const float p1 = __builtin_fmaf(re1, re1, im1 * im1);

    // rows r = 2w+i: z0 sign = r&8 = w&4; z1 = r&4 = w&2; z2 = r&2 = w&1; z3 = r&1 = i
    const float S = p0 + p1;
    const float D = p0 - p1;
    const float g0 = (w & 4) ? -S : S;
    const float g1 = (w & 2) ? -S : S;
    const float g2 = (w & 1) ? -S : S;
    sEv[w * 64 + e] = make_float4(g0, g1, g2, D);
    __syncthreads();

    if (tid < 64) {
        float4 a0 = sEv[tid];
#pragma unroll
        for (int ww = 1; ww < 8; ++ww) {
            const float4 t = sEv[ww * 64 + tid];
            a0.x += t.x; a0.y += t.y; a0.z += t.z; a0.w += t.w;
        }
        out[blockIdx.x * 64 + tid] = a0;
    }
}

extern "C" void kernel_launch(void* const* d_in, const int* in_sizes, int n_in,
                              void* d_out, int out_size, void* d_ws, size_t ws_size,
                              hipStream_t stream) {
    const float4* x = (const float4*)d_in[0];   // [B,4] f32
    const float*  w = (const float*)d_in[1];    // [6,4,3] f32
    float* V = (float*)d_ws;                    // 16*16*2 floats = 2 KB scratch
    float4* out = (float4*)d_out;               // [B,4] f32

    prep_kernel<<<1, 64, 0, stream>>>(w, V);
    qmain_kernel<<<BATCH / 64, 512, 0, stream>>>(x, V, out);
}